// Round 5
// baseline (865.575 us; speedup 1.0000x reference)
//
#include <hip/hip_runtime.h>

#define DIN 128
#define DOUT 128
#define TILE_N 32

typedef float f4 __attribute__((ext_vector_type(4)));

// One edge per 128 threads; thread d handles feature d.
__global__ void scatter_kernel(const float* __restrict__ x,
                               const int* __restrict__ src,
                               const int* __restrict__ dst,
                               float* __restrict__ agg,
                               float* __restrict__ deg,
                               int nE) {
    long long idx = (long long)blockIdx.x * blockDim.x + threadIdx.x;
    int e = (int)(idx >> 7);
    int d = (int)(idx & 127);
    if (e >= nE) return;
    int s = src[e];
    int t = dst[e];
    float v = x[(long long)s * DIN + d];
    atomicAdd(&agg[(long long)t * DIN + d], v);
    if (d == 0) atomicAdd(&deg[t], 1.0f);
}

// out[n0..n0+31][:] (+)= (A/deg) @ W [+ bias] [relu]
__global__ __launch_bounds__(256, 2)
void gemm_kernel(const float* __restrict__ A,    // [N,128]
                 const float* __restrict__ deg,  // [N] or null (scale=1)
                 const float* __restrict__ W,    // [128,128]
                 const float* __restrict__ bias, // [128] or null
                 float* __restrict__ out,        // [N,128]
                 int nN, int accumulate, int applyRelu) {
    __shared__ float Ws[DIN * DOUT];        // 64 KB
    __shared__ float As[TILE_N * DIN];      // 16 KB
    __shared__ float sInv[TILE_N];

    const int tid = threadIdx.x;
    const int n0 = blockIdx.x * TILE_N;

    // Stage W: 16384 floats = 4096 float4, 16 per thread, coalesced.
    {
        const f4* Wv = (const f4*)W;
        f4* Wsv = (f4*)Ws;
        #pragma unroll
        for (int i = 0; i < 16; i++) Wsv[tid + i * 256] = Wv[tid + i * 256];
    }
    // Stage A tile: 4096 floats = 1024 float4, 4 per thread.
    {
        const f4* Av = (const f4*)(A + (long long)n0 * DIN);
        f4* Asv = (f4*)As;
        #pragma unroll
        for (int i = 0; i < 4; i++) {
            int li = tid + i * 256;
            int row = n0 + (li >> 5);
            if (row < nN) Asv[li] = Av[li];
        }
    }
    if (tid < TILE_N) {
        int row = n0 + tid;
        float s = 1.0f;
        if (deg != nullptr) {
            float dd = (row < nN) ? deg[row] : 1.0f;
            s = 1.0f / fmaxf(dd, 1.0f);
        }
        sInv[tid] = s;
    }
    __syncthreads();

    const int tx = tid & 31;   // dout group: columns tx*4..tx*4+3
    const int ty = tid >> 5;   // node group: rows ty*4..ty*4+3
    const int dbase = tx * 4;
    const int nbase = ty * 4;

    f4 acc[4];
    #pragma unroll
    for (int j = 0; j < 4; j++) acc[j] = (f4)(0.0f);

    for (int k0 = 0; k0 < DIN; k0 += 4) {
        f4 a[4], w[4];
        #pragma unroll
        for (int j = 0; j < 4; j++)
            a[j] = *(const f4*)&As[(nbase + j) * DIN + k0];
        #pragma unroll
        for (int kk = 0; kk < 4; kk++)
            w[kk] = *(const f4*)&Ws[(k0 + kk) * DOUT + dbase];
        #pragma unroll
        for (int j = 0; j < 4; j++) {
            #pragma unroll
            for (int kk = 0; kk < 4; kk++) {
                acc[j] += a[j][kk] * w[kk];
            }
        }
    }

    #pragma unroll
    for (int j = 0; j < 4; j++) {
        int row = n0 + nbase + j;
        if (row >= nN) continue;
        float s = sInv[nbase + j];
        f4 r = acc[j] * s;
        f4* op = (f4*)&out[(long long)row * DOUT + dbase];
        if (accumulate) r += *op;
        if (bias != nullptr) r += *(const f4*)&bias[dbase];
        if (applyRelu) {
            r.x = fmaxf(r.x, 0.0f);
            r.y = fmaxf(r.y, 0.0f);
            r.z = fmaxf(r.z, 0.0f);
            r.w = fmaxf(r.w, 0.0f);
        }
        *op = r;
    }
}

extern "C" void kernel_launch(void* const* d_in, const int* in_sizes, int n_in,
                              void* d_out, int out_size, void* d_ws, size_t ws_size,
                              hipStream_t stream) {
    const float* x  = (const float*)d_in[0];
    const float* W  = (const float*)d_in[1];
    const float* Wl = (const float*)d_in[2];
    const float* b  = (const float*)d_in[3];
    const int* src  = (const int*)d_in[4];
    const int* dst  = (const int*)d_in[5];
    float* out = (float*)d_out;

    const int N = in_sizes[0] / DIN;
    const int R = in_sizes[1] / (DIN * DOUT);
    const int E = in_sizes[4] / R;

    float* agg = (float*)d_ws;                  // [N,128]
    float* deg = agg + (size_t)N * DIN;         // [N]

    const int gemmGrid = (N + TILE_N - 1) / TILE_N;
    const int scatGrid = (int)(((long long)E * 128 + 255) / 256);

    // Pass 1: self-loop, overwrite out = x @ Wl + b.
    gemm_kernel<<<gemmGrid, 256, 0, stream>>>(x, nullptr, Wl, b, out, N, 0, 0);

    for (int r = 0; r < R; r++) {
        hipMemsetAsync(agg, 0, ((size_t)N * DIN + N) * sizeof(float), stream);
        scatter_kernel<<<scatGrid, 256, 0, stream>>>(
            x, src + (size_t)r * E, dst + (size_t)r * E, agg, deg, E);
        gemm_kernel<<<gemmGrid, 256, 0, stream>>>(
            agg, deg, W + (size_t)r * DIN * DOUT, nullptr, out, N,
            /*accumulate=*/1, /*applyRelu=*/(r == R - 1) ? 1 : 0);
    }
}

// Round 6
// 381.320 us; speedup vs baseline: 2.2699x; 2.2699x over previous
//
#include <hip/hip_runtime.h>

#define DIN 128
#define DOUT 128

typedef float f4 __attribute__((ext_vector_type(4)));
typedef float f32x4 __attribute__((ext_vector_type(4)));
typedef short bf16x8 __attribute__((ext_vector_type(8)));

__device__ inline unsigned short f2bf(float f) {
    unsigned u = __float_as_uint(f);
    u += 0x7FFFu + ((u >> 16) & 1u);   // round-to-nearest-even
    return (unsigned short)(u >> 16);
}

// Build Wt[m][dout][din] bf16 from W[r][din][dout] (m=0..3) and Wl[din][dout] (m=4).
__global__ void prep_w(const float* __restrict__ W, const float* __restrict__ Wl,
                       unsigned short* __restrict__ Wt, int total) {
    int id = blockIdx.x * 256 + threadIdx.x;
    if (id >= total) return;
    int m    = id >> 14;          // 16384 = 128*128
    int rem  = id & 16383;
    int din  = rem >> 7;
    int dout = rem & 127;         // consecutive tid -> consecutive dout -> coalesced reads
    float v = (m < 4) ? W[(m << 14) + din * DOUT + dout] : Wl[din * DOUT + dout];
    Wt[(m << 14) + dout * DIN + din] = f2bf(v);
}

__global__ void deg_count(const int* __restrict__ dst, float* __restrict__ deg,
                          int E, int N, int total) {
    int i = blockIdx.x * 256 + threadIdx.x;
    if (i >= total) return;
    int r = i / E;
    atomicAdd(&deg[(long long)r * N + dst[i]], 1.0f);
}

// One wave per 16 edges: y = bf16(x[src]) @ bf16(W_r); out[dst] += y / max(deg,1).
__global__ __launch_bounds__(256)
void edge_gemm(const float* __restrict__ x,
               const int* __restrict__ src,
               const int* __restrict__ dst,
               const unsigned short* __restrict__ Wt,  // [4][dout=128][din=128] bf16
               const float* __restrict__ deg,          // [4][N]
               float* __restrict__ out,                // [N][128]
               int E, int N) {
    const int lane = threadIdx.x & 63;
    const int w    = threadIdx.x >> 6;
    const int geW  = blockIdx.x * 64 + w * 16;   // wave's first (global) edge
    const int r    = geW / E;                    // 16 | E so no straddle
    const int lr   = lane & 15;
    const int kg   = lane >> 4;

    const int s = src[geW + lr];                 // A-row for this lane = edge (geW+lr)
    const float* xrow = x + (long long)s * DIN;
    const unsigned short* WtR = Wt + (r << 14);

    f32x4 acc[8];
    #pragma unroll
    for (int ct = 0; ct < 8; ct++) acc[ct] = (f32x4)(0.0f);

    #pragma unroll
    for (int k0 = 0; k0 < DIN; k0 += 32) {
        const float* ap = xrow + k0 + kg * 8;
        f4 alo = *(const f4*)ap;
        f4 ahi = *(const f4*)(ap + 4);
        bf16x8 a;
        a[0] = (short)f2bf(alo[0]); a[1] = (short)f2bf(alo[1]);
        a[2] = (short)f2bf(alo[2]); a[3] = (short)f2bf(alo[3]);
        a[4] = (short)f2bf(ahi[0]); a[5] = (short)f2bf(ahi[1]);
        a[6] = (short)f2bf(ahi[2]); a[7] = (short)f2bf(ahi[3]);
        #pragma unroll
        for (int ct = 0; ct < 8; ct++) {
            bf16x8 b = *(const bf16x8*)&WtR[((ct * 16 + lr) << 7) + k0 + kg * 8];
            acc[ct] = __builtin_amdgcn_mfma_f32_16x16x32_bf16(a, b, acc[ct], 0, 0, 0);
        }
    }

    // D[m][n]: n = lane&15, m = (lane>>4)*4 + j  (m = edge within tile)
    const float* degr = deg + (long long)r * N;
    #pragma unroll
    for (int j = 0; j < 4; j++) {
        int t = dst[geW + kg * 4 + j];
        float sc = 1.0f / fmaxf(degr[t], 1.0f);
        float* orow = out + (long long)t * DOUT + lr;
        #pragma unroll
        for (int ct = 0; ct < 8; ct++)
            atomicAdd(orow + ct * 16, acc[ct][j] * sc);
    }
}

// out = relu(out + bf16(x) @ bf16(Wl) + b), in place. One wave per 16 node rows.
__global__ __launch_bounds__(256)
void self_gemm(const float* __restrict__ x,
               const unsigned short* __restrict__ WtS,  // [dout=128][din=128] bf16
               const float* __restrict__ bias,
               float* __restrict__ out, int N) {
    const int lane = threadIdx.x & 63;
    const int w    = threadIdx.x >> 6;
    const int n0   = blockIdx.x * 64 + w * 16;
    const int lr   = lane & 15;
    const int kg   = lane >> 4;

    const int na = n0 + lr;
    const bool av = (na < N);
    const float* xrow = x + (long long)(av ? na : 0) * DIN;

    f32x4 acc[8];
    #pragma unroll
    for (int ct = 0; ct < 8; ct++) acc[ct] = (f32x4)(0.0f);

    #pragma unroll
    for (int k0 = 0; k0 < DIN; k0 += 32) {
        bf16x8 a;
        if (av) {
            const float* ap = xrow + k0 + kg * 8;
            f4 alo = *(const f4*)ap;
            f4 ahi = *(const f4*)(ap + 4);
            a[0] = (short)f2bf(alo[0]); a[1] = (short)f2bf(alo[1]);
            a[2] = (short)f2bf(alo[2]); a[3] = (short)f2bf(alo[3]);
            a[4] = (short)f2bf(ahi[0]); a[5] = (short)f2bf(ahi[1]);
            a[6] = (short)f2bf(ahi[2]); a[7] = (short)f2bf(ahi[3]);
        } else {
            #pragma unroll
            for (int i = 0; i < 8; i++) a[i] = 0;
        }
        #pragma unroll
        for (int ct = 0; ct < 8; ct++) {
            bf16x8 b = *(const bf16x8*)&WtS[((ct * 16 + lr) << 7) + k0 + kg * 8];
            acc[ct] = __builtin_amdgcn_mfma_f32_16x16x32_bf16(a, b, acc[ct], 0, 0, 0);
        }
    }

    #pragma unroll
    for (int j = 0; j < 4; j++) {
        int n2 = n0 + kg * 4 + j;
        if (n2 >= N) continue;
        float* orow = out + (long long)n2 * DOUT + lr;
        #pragma unroll
        for (int ct = 0; ct < 8; ct++) {
            float v = orow[ct * 16] + acc[ct][j] + bias[ct * 16 + lr];
            orow[ct * 16] = fmaxf(v, 0.0f);
        }
    }
}

extern "C" void kernel_launch(void* const* d_in, const int* in_sizes, int n_in,
                              void* d_out, int out_size, void* d_ws, size_t ws_size,
                              hipStream_t stream) {
    const float* x  = (const float*)d_in[0];
    const float* W  = (const float*)d_in[1];
    const float* Wl = (const float*)d_in[2];
    const float* b  = (const float*)d_in[3];
    const int* src  = (const int*)d_in[4];
    const int* dst  = (const int*)d_in[5];
    float* out = (float*)d_out;

    const int N = in_sizes[0] / DIN;
    const int R = in_sizes[1] / (DIN * DOUT);
    const int E = in_sizes[4] / R;

    unsigned short* Wt = (unsigned short*)d_ws;            // 5*16384 bf16 = 160 KB
    float* deg = (float*)(Wt + 5 * 16384);                 // [R][N] floats

    hipMemsetAsync(out, 0, (size_t)out_size * sizeof(float), stream);
    hipMemsetAsync(deg, 0, (size_t)R * N * sizeof(float), stream);

    const int wTotal = 5 * DIN * DOUT;
    prep_w<<<(wTotal + 255) / 256, 256, 0, stream>>>(W, Wl, Wt, wTotal);

    const int totE = R * E;
    deg_count<<<(totE + 255) / 256, 256, 0, stream>>>(dst, deg, E, N, totE);

    edge_gemm<<<totE / 64, 256, 0, stream>>>(x, src, dst, Wt, deg, out, E, N);

    self_gemm<<<(N + 63) / 64, 256, 0, stream>>>(x, Wt + 4 * 16384, b, out, N);
}

// Round 7
// 298.862 us; speedup vs baseline: 2.8962x; 1.2759x over previous
//
#include <hip/hip_runtime.h>

#define DIN 128
#define DOUT 128

typedef float f4 __attribute__((ext_vector_type(4)));
typedef float f32x4 __attribute__((ext_vector_type(4)));
typedef short bf16x8 __attribute__((ext_vector_type(8)));
typedef unsigned short u16x8 __attribute__((ext_vector_type(8)));

__device__ inline unsigned short f2bf(float f) {
    unsigned u = __float_as_uint(f);
    u += 0x7FFFu + ((u >> 16) & 1u);   // round-to-nearest-even
    return (unsigned short)(u >> 16);
}

// Build Wt[m][dout][din] bf16 from W[r][din][dout] (m=0..3) and Wl[din][dout] (m=4).
__global__ void prep_w(const float* __restrict__ W, const float* __restrict__ Wl,
                       unsigned short* __restrict__ Wt, int total) {
    int id = blockIdx.x * 256 + threadIdx.x;
    if (id >= total) return;
    int m    = id >> 14;
    int rem  = id & 16383;
    int din  = rem >> 7;
    int dout = rem & 127;
    float v = (m < 4) ? W[(m << 14) + din * DOUT + dout] : Wl[din * DOUT + dout];
    Wt[(m << 14) + dout * DIN + din] = f2bf(v);
}

__global__ void deg_count(const int* __restrict__ dst, int* __restrict__ cnt,
                          int E, int N, int total) {
    int i = blockIdx.x * 256 + threadIdx.x;
    if (i >= total) return;
    int r = i / E;
    atomicAdd(&cnt[r * N + dst[i]], 1);
}

// ---- 3-pass exclusive scan over M = R*N ints (2048 items / block) ----
__global__ void scan1(const int* __restrict__ cnt, int* __restrict__ off,
                      int* __restrict__ part, int M) {
    __shared__ int sd[256];
    const int t = threadIdx.x, b = blockIdx.x;
    const int base = b * 2048 + t * 8;
    int v[8]; int tsum = 0;
    #pragma unroll
    for (int i = 0; i < 8; i++) { int g = base + i; v[i] = (g < M) ? cnt[g] : 0; tsum += v[i]; }
    sd[t] = tsum; __syncthreads();
    for (int d = 1; d < 256; d <<= 1) {
        int val = 0;
        if (t >= d) val = sd[t - d];
        __syncthreads();
        if (t >= d) sd[t] += val;
        __syncthreads();
    }
    int run = sd[t] - tsum;
    if (t == 255) part[b] = sd[255];
    #pragma unroll
    for (int i = 0; i < 8; i++) { int g = base + i; if (g < M) off[g] = run; run += v[i]; }
}

// Single block; requires nb <= 256 (R*N=400k -> nb=196).
__global__ void scan2(int* __restrict__ part, int nb, int* __restrict__ offM) {
    __shared__ int sd[256];
    const int t = threadIdx.x;
    int v = (t < nb) ? part[t] : 0;
    sd[t] = v; __syncthreads();
    for (int d = 1; d < 256; d <<= 1) {
        int val = 0;
        if (t >= d) val = sd[t - d];
        __syncthreads();
        if (t >= d) sd[t] += val;
        __syncthreads();
    }
    if (t < nb) part[t] = sd[t] - v;
    if (t == 255) *offM = sd[255];
}

__global__ void scan3(int* __restrict__ off, const int* __restrict__ part, int M) {
    const int add = part[blockIdx.x];
    const int base = blockIdx.x * 2048 + threadIdx.x;
    #pragma unroll
    for (int i = 0; i < 8; i++) { int g = base + i * 256; if (g < M) off[g] += add; }
}

// Scatter src ids into CSR slots; decrements cnt back to 0 (used as cursor).
__global__ void fill_csr(const int* __restrict__ src, const int* __restrict__ dst,
                         const int* __restrict__ off, int* __restrict__ cnt,
                         int* __restrict__ csr, int E, int N, int total) {
    int i = blockIdx.x * 256 + threadIdx.x;
    if (i >= total) return;
    int r = i / E;
    int idx = r * N + dst[i];
    int pos = atomicAdd(&cnt[idx], -1) - 1;
    csr[off[idx] + pos] = src[i];
}

// Block = 64 dst nodes. 5 phases (4 relations + self): gather-mean in fp32 regs,
// bf16 -> LDS tile, MFMA-accumulate. Epilogue: +bias, ReLU, single out write.
__global__ __launch_bounds__(256)
void fused(const float* __restrict__ x, const int* __restrict__ off,
           const int* __restrict__ csr, const unsigned short* __restrict__ Wt,
           const float* __restrict__ bias, float* __restrict__ out, int N) {
    __shared__ unsigned short As[64 * 136];   // [64][128 + 8 pad] bf16, 17.4 KB

    const int t    = threadIdx.x;
    const int lane = t & 63;
    const int w    = t >> 6;
    const int n0   = blockIdx.x * 64;
    const int myN  = t >> 2;            // node within tile (0..63)
    const int myC  = (t & 3) * 32;      // feature chunk base
    const int node = n0 + myN;
    const bool nv  = node < N;
    const int lr   = lane & 15;
    const int kg   = lane >> 4;

    f32x4 acc[8];
    #pragma unroll
    for (int ct = 0; ct < 8; ct++) acc[ct] = (f32x4)(0.0f);

    for (int r = 0; r < 5; r++) {
        float agg[32];
        if (r < 4) {
            #pragma unroll
            for (int i = 0; i < 32; i++) agg[i] = 0.0f;
            int s0 = 0, s1 = 0;
            if (nv) {
                int idx = r * N + node;
                s0 = off[idx];
                s1 = off[idx + 1];   // off has R*N+1 entries; boundaries are contiguous
            }
            for (int e = s0; e < s1; e++) {
                const float* xr = x + (long long)csr[e] * DIN + myC;
                #pragma unroll
                for (int c = 0; c < 8; c++) {
                    f4 v = *(const f4*)(xr + c * 4);
                    agg[c*4+0] += v[0]; agg[c*4+1] += v[1];
                    agg[c*4+2] += v[2]; agg[c*4+3] += v[3];
                }
            }
            float sc = 1.0f / fmaxf((float)(s1 - s0), 1.0f);
            #pragma unroll
            for (int i = 0; i < 32; i++) agg[i] *= sc;
        } else {
            // self-loop: A row is x[node] itself
            const float* xr = x + (long long)(nv ? node : 0) * DIN + myC;
            #pragma unroll
            for (int c = 0; c < 8; c++) {
                f4 v = *(const f4*)(xr + c * 4);
                agg[c*4+0] = v[0]; agg[c*4+1] = v[1];
                agg[c*4+2] = v[2]; agg[c*4+3] = v[3];
            }
        }

        // previous MFMA phase must be done reading As before we overwrite
        __syncthreads();
        #pragma unroll
        for (int c = 0; c < 4; c++) {
            u16x8 p;
            #pragma unroll
            for (int i = 0; i < 8; i++) p[i] = f2bf(agg[c * 8 + i]);
            *(u16x8*)&As[myN * 136 + myC + c * 8] = p;
        }
        __syncthreads();

        const unsigned short* WtR = Wt + (r << 14);
        #pragma unroll
        for (int k0 = 0; k0 < DIN; k0 += 32) {
            bf16x8 a = *(const bf16x8*)&As[(w * 16 + lr) * 136 + k0 + kg * 8];
            #pragma unroll
            for (int ct = 0; ct < 8; ct++) {
                bf16x8 bfr = *(const bf16x8*)&WtR[((ct * 16 + lr) << 7) + k0 + kg * 8];
                acc[ct] = __builtin_amdgcn_mfma_f32_16x16x32_bf16(a, bfr, acc[ct], 0, 0, 0);
            }
        }
    }

    // D[m][n]: n = lane&15 (dout within 16-block), m = kg*4 + j (node within wave tile)
    #pragma unroll
    for (int j = 0; j < 4; j++) {
        int n2 = n0 + w * 16 + kg * 4 + j;
        if (n2 >= N) continue;
        float* orow = out + (long long)n2 * DOUT + lr;
        #pragma unroll
        for (int ct = 0; ct < 8; ct++) {
            float v = acc[ct][j] + bias[ct * 16 + lr];
            orow[ct * 16] = fmaxf(v, 0.0f);
        }
    }
}

extern "C" void kernel_launch(void* const* d_in, const int* in_sizes, int n_in,
                              void* d_out, int out_size, void* d_ws, size_t ws_size,
                              hipStream_t stream) {
    const float* x  = (const float*)d_in[0];
    const float* W  = (const float*)d_in[1];
    const float* Wl = (const float*)d_in[2];
    const float* b  = (const float*)d_in[3];
    const int* src  = (const int*)d_in[4];
    const int* dst  = (const int*)d_in[5];
    float* out = (float*)d_out;

    const int N = in_sizes[0] / DIN;
    const int R = in_sizes[1] / (DIN * DOUT);
    const int E = in_sizes[4] / R;
    const int M = R * N;
    const int totE = R * E;

    // workspace layout
    unsigned short* Wt = (unsigned short*)d_ws;        // 5*16384 bf16 = 160 KB
    int* cnt  = (int*)((char*)d_ws + 5 * 16384 * 2);   // [M]
    int* off  = cnt + M;                               // [M+1]
    int* part = off + M + 1;                           // [256]
    int* csr  = part + 256;                            // [R*E]

    hipMemsetAsync(cnt, 0, (size_t)M * sizeof(int), stream);

    prep_w<<<(5 * DIN * DOUT + 255) / 256, 256, 0, stream>>>(W, Wl, Wt, 5 * DIN * DOUT);

    deg_count<<<(totE + 255) / 256, 256, 0, stream>>>(dst, cnt, E, N, totE);

    const int nb = (M + 2047) / 2048;                  // 196 for R*N = 400k
    scan1<<<nb, 256, 0, stream>>>(cnt, off, part, M);
    scan2<<<1, 256, 0, stream>>>(part, nb, off + M);
    scan3<<<nb, 256, 0, stream>>>(off, part, M);

    fill_csr<<<(totE + 255) / 256, 256, 0, stream>>>(src, dst, off, cnt, csr, E, N, totE);

    fused<<<(N + 63) / 64, 256, 0, stream>>>(x, off, csr, Wt, b, out, N);
}